// Round 3
// baseline (1010.240 us; speedup 1.0000x reference)
//
#include <hip/hip_runtime.h>
#include <hip/hip_fp16.h>
#include <math.h>

namespace {
constexpr int S = 192;
constexpr long long S2 = (long long)S * S;
constexpr long long S3 = (long long)S * S2;
constexpr int NB = 4;      // batch
constexpr int K = 11;
constexpr int R = 5;       // radius
constexpr int HCH = 48;    // A: h-outputs per block (4 chunks)
constexpr int DCH = 96;    // B: d-outputs per block (2 chunks)
constexpr float C1f = 1e-4f;
constexpr float C2f = 9e-4f;

struct GaussW { float g[K]; };

__global__ void k_init(double* acc) { *acc = 0.0; }

__global__ void k_final(const double* __restrict__ acc, float* __restrict__ out) {
  out[0] = (float)(acc[0] / (double)(NB * S3));
}

// ---- Kernel A: fused W-blur + H-blur, fp16 pair-packed outputs ----
// grid = (dz=S, hchunk=4, n); block = 192 (w). Stages 11 raw rows per barrier
// pair; register ring over h with compile-time modular slots (no shifts).
__global__ __launch_bounds__(192) void k_blurWH(
    const float* __restrict__ gt, const float* __restrict__ pr,
    __half2* __restrict__ p01, __half2* __restrict__ p23, __half* __restrict__ p4,
    long long in_base, GaussW Wt) {
  __shared__ float2 rowbuf[K][208];  // [8..199] data, [0..7]/[200..207] zero pads
  const int w = threadIdx.x;
  const int dz = blockIdx.x;
  const int h0 = (int)blockIdx.y * HCH;
  const long long n = blockIdx.z;
  const float* pg = gt + in_base + (n * S + dz) * S2;
  const float* pp = pr + in_base + (n * S + dz) * S2;
  const long long obase = (n * S + dz) * S2 + w;

  // zero the halo pads once (176 entries, threads 0..175)
  if (w < 176) {
    int j = w >> 4, q = w & 15;
    rowbuf[j][(q < 8) ? q : (192 + q)] = make_float2(0.f, 0.f);
  }

  float2 w01[K], w23[K];
  float w4v[K];
#pragma unroll
  for (int i = 0; i < K; ++i) {
    w01[i] = make_float2(0.f, 0.f);
    w23[i] = make_float2(0.f, 0.f);
    w4v[i] = 0.f;
  }

  // source rows: h0-5 .. h0+52 (58), as 5 full batches of 11 + tail of 3.
  for (int b = 0; b < 6; ++b) {
    const int nrows = (b < 5) ? K : 3;
    const int r0 = h0 - R + b * K;
    if (b) __syncthreads();
    // stage nrows raw rows (zero outside the volume)
    for (int j = 0; j < nrows; ++j) {
      int r = r0 + j;
      float a = 0.f, bb = 0.f;
      if ((unsigned)r < (unsigned)S) {
        a = pg[(long long)r * S + w];
        bb = pp[(long long)r * S + w];
      }
      rowbuf[j][8 + w] = make_float2(a, bb);
    }
    __syncthreads();
    // consume: W-blur each row, push to ring, emit H-blurred output
#pragma unroll
    for (int j = 0; j < K; ++j) {
      if (j >= nrows) break;  // only trims the tail batch (uniform)
      float2 s01 = make_float2(0.f, 0.f), s23 = make_float2(0.f, 0.f);
      float s4 = 0.f;
#pragma unroll
      for (int i = 0; i < K; ++i) {
        float2 ab = rowbuf[j][w + 3 + i];
        float g = Wt.g[i];
        s01.x = fmaf(g, ab.x, s01.x);
        s01.y = fmaf(g, ab.y, s01.y);
        float ta = g * ab.x, tb = g * ab.y;
        s23.x = fmaf(ta, ab.x, s23.x);
        s23.y = fmaf(tb, ab.y, s23.y);
        s4 = fmaf(ta, ab.y, s4);
      }
      w01[j] = s01; w23[j] = s23; w4v[j] = s4;  // slot = counter % 11 = j
      if (b > 0 || j == K - 1) {  // counter >= 10 -> output h = h0 + c - 10
        float2 m01 = make_float2(0.f, 0.f), m23 = make_float2(0.f, 0.f);
        float m4 = 0.f;
#pragma unroll
        for (int i = 0; i < K; ++i) {
          int sl = (j + 1 + i) % K;  // compile-time
          float g = Wt.g[i];
          m01.x = fmaf(g, w01[sl].x, m01.x);
          m01.y = fmaf(g, w01[sl].y, m01.y);
          m23.x = fmaf(g, w23[sl].x, m23.x);
          m23.y = fmaf(g, w23[sl].y, m23.y);
          m4 = fmaf(g, w4v[sl], m4);
        }
        const long long o = obase + (long long)(h0 + b * K + j - 2 * R) * S;
        p01[o] = __floats2half2_rn(m01.x, m01.y);
        p23[o] = __floats2half2_rn(m23.x, m23.y);
        p4[o] = __float2half(m4);
      }
    }
  }
}

// ---- Kernel B: D-blur + SSIM + mean-reduce ----
// grid = (h=S, n, dchunk=2); block = 192 (w). Ring with compile-time slots,
// unrolled by 11 so loads software-pipeline within each body.
__global__ __launch_bounds__(192) void k_blurD_ssim(
    const __half2* __restrict__ p01, const __half2* __restrict__ p23,
    const __half* __restrict__ p4, double* __restrict__ acc, GaussW Wt) {
  const int w = threadIdx.x;
  const int h = blockIdx.x;
  const long long n = blockIdx.y;
  const int d0 = (int)blockIdx.z * DCH;
  const long long base = n * S3 + (long long)h * S + w;
  const __half2* q01 = p01 + base;
  const __half2* q23 = p23 + base;
  const __half* q4 = p4 + base;

  float2 w01[K], w23[K];
  float w4v[K];
  // preload counters 0..9 -> planes d0-5 .. d0+4 (slot = counter)
#pragma unroll
  for (int c = 0; c < K - 1; ++c) {
    int d = d0 - R + c;
    float2 a = make_float2(0.f, 0.f), bb = make_float2(0.f, 0.f);
    float e = 0.f;
    if (d >= 0) {
      long long o = (long long)d * S2;
      a = __half22float2(q01[o]);
      bb = __half22float2(q23[o]);
      e = __half2float(q4[o]);
    }
    w01[c] = a; w23[c] = bb; w4v[c] = e;
  }
  w01[K - 1] = make_float2(0.f, 0.f);
  w23[K - 1] = make_float2(0.f, 0.f);
  w4v[K - 1] = 0.f;

  double lsum = 0.0;

  auto step = [&](int b, int j, bool guard_d) {
    const int dld = d0 + R + b * K + j;     // plane entering the ring
    const long long o = (long long)dld * S2;
    float2 a = make_float2(0.f, 0.f), bb = make_float2(0.f, 0.f);
    float e = 0.f;
    if (!guard_d || dld < S) {
      a = __half22float2(q01[o]);
      bb = __half22float2(q23[o]);
      e = __half2float(q4[o]);
    }
    const int sw = (j + 10) % K;            // compile-time slot to write
    w01[sw] = a; w23[sw] = bb; w4v[sw] = e;
    float2 m01 = make_float2(0.f, 0.f), m23 = make_float2(0.f, 0.f);
    float m4 = 0.f;
#pragma unroll
    for (int i = 0; i < K; ++i) {
      int sl = (j + i) % K;                 // compile-time
      float g = Wt.g[i];
      m01.x = fmaf(g, w01[sl].x, m01.x);
      m01.y = fmaf(g, w01[sl].y, m01.y);
      m23.x = fmaf(g, w23[sl].x, m23.x);
      m23.y = fmaf(g, w23[sl].y, m23.y);
      m4 = fmaf(g, w4v[sl], m4);
    }
    float mux = m01.x, muy = m01.y, bxx = m23.x, byy = m23.y, bxy = m4;
    float mux2 = mux * mux, muy2 = muy * muy, muxy = mux * muy;
    float sx = bxx - mux2, sy = byy - muy2, sxy = bxy - muxy;
    float num = fmaf(2.f, muxy, C1f) * fmaf(2.f, sxy, C2f);
    float den = (mux2 + muy2 + C1f) * (sx + sy + C2f);
    float q = num * __builtin_amdgcn_rcpf(den);
    lsum += (double)(1.f - q);
  };

  for (int b = 0; b < DCH / K; ++b) {       // 8 full bodies of 11 (d <= d0+92 < S)
#pragma unroll
    for (int j = 0; j < K; ++j) step(b, j, false);
  }
#pragma unroll
  for (int j = 0; j < DCH - K * (DCH / K); ++j) step(DCH / K, j, true);  // tail 8

  // block reduction: wave shuffle -> LDS -> one atomic per block
  double v = lsum;
#pragma unroll
  for (int o = 32; o > 0; o >>= 1) v += __shfl_down(v, o, 64);
  __shared__ double wsum[3];
  int lane = threadIdx.x & 63, wv = threadIdx.x >> 6;
  if (lane == 0) wsum[wv] = v;
  __syncthreads();
  if (threadIdx.x == 0) atomicAdd(acc, wsum[0] + wsum[1] + wsum[2]);
}

}  // namespace

extern "C" void kernel_launch(void* const* d_in, const int* in_sizes, int n_in,
                              void* d_out, int out_size, void* d_ws, size_t ws_size,
                              hipStream_t stream) {
  (void)in_sizes; (void)n_in; (void)out_size;
  const float* gt = (const float*)d_in[0];
  const float* pr = (const float*)d_in[1];
  float* out = (float*)d_out;
  double* acc = (double*)d_ws;

  GaussW W;
  {
    double gg[K], sum = 0.0;
    for (int i = 0; i < K; ++i) {
      double x = (double)(i - K / 2);
      gg[i] = exp(-(x * x) / (2.0 * 1.5 * 1.5)) / (sqrt(2.0 * M_PI) * 1.5);
      sum += gg[i];
    }
    for (int i = 0; i < K; ++i) W.g[i] = (float)(gg[i] / sum);
  }

  auto run = [&](long long base_n, int nb) {
    size_t vox = (size_t)nb * S3;
    __half2* p01 = (__half2*)((char*)d_ws + 256);
    __half2* p23 = p01 + vox;
    __half* p4 = (__half*)(p23 + vox);
    k_blurWH<<<dim3(S, S / HCH, nb), dim3(192), 0, stream>>>(
        gt, pr, p01, p23, p4, base_n * S3, W);
    k_blurD_ssim<<<dim3(S, nb, S / DCH), dim3(192), 0, stream>>>(
        p01, p23, p4, acc, W);
  };
  auto need = [](int nb) { return (size_t)256 + (size_t)nb * S3 * 10; };  // 4+4+2 B/voxel

  k_init<<<dim3(1), dim3(1), 0, stream>>>(acc);
  if (ws_size >= need(4)) {
    run(0, 4);
  } else if (ws_size >= need(2)) {
    run(0, 2);
    run(2, 2);
  } else {
    for (int g = 0; g < NB; ++g) run(g, 1);
  }
  k_final<<<dim3(1), dim3(1), 0, stream>>>(acc, out);
}

// Round 5
// 455.083 us; speedup vs baseline: 2.2199x; 2.2199x over previous
//
#include <hip/hip_runtime.h>
#include <hip/hip_fp16.h>
#include <math.h>

namespace {
constexpr int S = 192;
constexpr long long S2 = (long long)S * S;
constexpr long long S3 = (long long)S * S2;
constexpr int NB = 4;
constexpr int K = 11;
constexpr int R = 5;
constexpr int HCH = 48;   // A: h-outputs per block (4 chunks)
constexpr int DCH = 48;   // B: d-outputs per block (4 chunks)
constexpr float C1f = 1e-4f;
constexpr float C2f = 9e-4f;

struct GaussW { float g[K]; };

__global__ void k_init(double* acc) { *acc = 0.0; }

__global__ void k_final(const double* __restrict__ acc, float* __restrict__ out) {
  out[0] = (float)(acc[0] / (double)(NB * S3));
}

// ======================= Kernel A helpers =======================
// All loops fully unrolled with template bounds: ring indices compile-time.

template <int N, bool GUARD>
__device__ __forceinline__ void loadA(const float* pg, const float* pp, int r0,
                                      int w, float (&la)[K], float (&lb)[K]) {
#pragma unroll
  for (int j = 0; j < N; ++j) {
    int r = r0 + j;
    bool ok = !GUARD || ((unsigned)r < (unsigned)S);
    la[j] = ok ? pg[(long long)r * S + w] : 0.f;
    lb[j] = ok ? pp[(long long)r * S + w] : 0.f;
  }
}

template <int N>
__device__ __forceinline__ void commitA(float2 (*rb)[208], int w,
                                        const float (&la)[K], const float (&lb)[K]) {
#pragma unroll
  for (int j = 0; j < N; ++j) rb[j][8 + w] = make_float2(la[j], lb[j]);
}

template <int NROWS, bool EMITALL>
__device__ __forceinline__ void consumeA(
    const float2 (*rb)[208], int w, const GaussW& Wt,
    float2 (&w01)[K], float2 (&w23)[K], float (&w4v)[K],
    __half2* p01, __half2* p23, __half* p4, long long obase, int hbase) {
#pragma unroll
  for (int j = 0; j < NROWS; ++j) {
    // W-blur the 5 products for staged row j
    float2 s01 = make_float2(0.f, 0.f), s23 = make_float2(0.f, 0.f);
    float s4 = 0.f;
#pragma unroll
    for (int i = 0; i < K; ++i) {
      float2 ab = rb[j][w + 3 + i];
      float g = Wt.g[i];
      s01.x = fmaf(g, ab.x, s01.x);
      s01.y = fmaf(g, ab.y, s01.y);
      float ta = g * ab.x, tb = g * ab.y;
      s23.x = fmaf(ta, ab.x, s23.x);
      s23.y = fmaf(tb, ab.y, s23.y);
      s4 = fmaf(ta, ab.y, s4);
    }
    w01[j] = s01; w23[j] = s23; w4v[j] = s4;  // slot = counter % 11 = j
    if (EMITALL || j == K - 1) {              // compile-time
      float2 m01 = make_float2(0.f, 0.f), m23 = make_float2(0.f, 0.f);
      float m4 = 0.f;
#pragma unroll
      for (int i = 0; i < K; ++i) {
        const int sl = (j + 1 + i) % K;       // compile-time
        float g = Wt.g[i];
        m01.x = fmaf(g, w01[sl].x, m01.x);
        m01.y = fmaf(g, w01[sl].y, m01.y);
        m23.x = fmaf(g, w23[sl].x, m23.x);
        m23.y = fmaf(g, w23[sl].y, m23.y);
        m4 = fmaf(g, w4v[sl], m4);
      }
      long long o = obase + (long long)(hbase + j) * S;
      p01[o] = __floats2half2_rn(m01.x, m01.y);
      p23[o] = __floats2half2_rn(m23.x, m23.y);
      p4[o] = __float2half(m4);
    }
  }
}

// ---- Kernel A: fused W+H blur -> 5 fp16 fields (pair-packed) ----
// grid = (dz=S, hchunk=4, n); block = 192 (w). 11-row batches, LDS
// double-buffer, loads register-staged one batch ahead. 6 barriers total.
// NOTE: batch4 (rows h0+39..h0+49) MUST be guarded: for h0=144 it touches
// rows 192..193 (OOB) -- this unguarded read was R4's memory-fault crash.
__global__ __launch_bounds__(192) void k_blurWH(
    const float* __restrict__ gt, const float* __restrict__ pr,
    __half2* __restrict__ p01, __half2* __restrict__ p23, __half* __restrict__ p4,
    long long in_base, GaussW Wt) {
  __shared__ float2 rowbuf[2][K][208];  // [8..199] data, pads zero
  const int w = threadIdx.x;
  const int dz = blockIdx.x;
  const int h0 = (int)blockIdx.y * HCH;
  const long long n = blockIdx.z;
  const float* pg = gt + in_base + (n * S + dz) * S2;
  const float* pp = pr + in_base + (n * S + dz) * S2;
  const long long obase = (n * S + dz) * S2 + w;

  if (w < 176) {  // zero halo pads of both buffers once
    int j = w >> 4, q = w & 15;
    int idx = (q < 8) ? q : (192 + q);
    rowbuf[0][j][idx] = make_float2(0.f, 0.f);
    rowbuf[1][j][idx] = make_float2(0.f, 0.f);
  }

  float2 w01[K], w23[K];
  float w4v[K];
  float la[K], lb[K];

  loadA<K, true>(pg, pp, h0 - R, w, la, lb);          // batch0 rows h0-5..h0+5
  commitA<K>(rowbuf[0], w, la, lb);
  __syncthreads();
  loadA<K, false>(pg, pp, h0 + 6, w, la, lb);         // batch1 (max row 160: safe)
  consumeA<K, false>(rowbuf[0], w, Wt, w01, w23, w4v, p01, p23, p4, obase, h0 - 10);
  commitA<K>(rowbuf[1], w, la, lb);
  __syncthreads();
  loadA<K, false>(pg, pp, h0 + 17, w, la, lb);        // batch2 (max row 171: safe)
  consumeA<K, true>(rowbuf[1], w, Wt, w01, w23, w4v, p01, p23, p4, obase, h0 + 1);
  commitA<K>(rowbuf[0], w, la, lb);
  __syncthreads();
  loadA<K, false>(pg, pp, h0 + 28, w, la, lb);        // batch3 (max row 182: safe)
  consumeA<K, true>(rowbuf[0], w, Wt, w01, w23, w4v, p01, p23, p4, obase, h0 + 12);
  commitA<K>(rowbuf[1], w, la, lb);
  __syncthreads();
  loadA<K, true>(pg, pp, h0 + 39, w, la, lb);         // batch4 (max row 193: GUARD)
  consumeA<K, true>(rowbuf[1], w, Wt, w01, w23, w4v, p01, p23, p4, obase, h0 + 23);
  commitA<K>(rowbuf[0], w, la, lb);
  __syncthreads();
  loadA<3, true>(pg, pp, h0 + 50, w, la, lb);         // batch5 (tail 3 rows, GUARD)
  consumeA<K, true>(rowbuf[0], w, Wt, w01, w23, w4v, p01, p23, p4, obase, h0 + 34);
  commitA<3>(rowbuf[1], w, la, lb);
  __syncthreads();
  consumeA<3, true>(rowbuf[1], w, Wt, w01, w23, w4v, p01, p23, p4, obase, h0 + 45);
}

// ======================= Kernel B helpers =======================

template <int N, bool GUARD>
__device__ __forceinline__ void stageB(const __half2* q01, const __half2* q23,
                                       const __half* q4, int plane0,
                                       __half2 (&sa)[K], __half2 (&sb)[K],
                                       __half (&se)[K]) {
  const __half2 z2 = __floats2half2_rn(0.f, 0.f);
  const __half z1 = __float2half(0.f);
#pragma unroll
  for (int j = 0; j < N; ++j) {
    int d = plane0 + j;
    bool ok = !GUARD || ((unsigned)d < (unsigned)S);
    long long o = (long long)d * S2;
    sa[j] = ok ? q01[o] : z2;
    sb[j] = ok ? q23[o] : z2;
    se[j] = ok ? q4[o] : z1;
  }
}

template <int NOUT>
__device__ __forceinline__ void consumeB(
    const __half2 (&sa)[K], const __half2 (&sb)[K], const __half (&se)[K],
    const GaussW& Wt, float2 (&r01)[K], float2 (&r23)[K], float (&r4)[K],
    double& lsum) {
  float fsum = 0.f;
#pragma unroll
  for (int j = 0; j < NOUT; ++j) {
    const int sw = (10 + j) % K;              // compile-time commit slot
    r01[sw] = __half22float2(sa[j]);
    r23[sw] = __half22float2(sb[j]);
    r4[sw] = __half2float(se[j]);
    float2 m01 = make_float2(0.f, 0.f), m23 = make_float2(0.f, 0.f);
    float m4 = 0.f;
#pragma unroll
    for (int i = 0; i < K; ++i) {
      const int sl = (j + i) % K;             // compile-time
      float g = Wt.g[i];
      m01.x = fmaf(g, r01[sl].x, m01.x);
      m01.y = fmaf(g, r01[sl].y, m01.y);
      m23.x = fmaf(g, r23[sl].x, m23.x);
      m23.y = fmaf(g, r23[sl].y, m23.y);
      m4 = fmaf(g, r4[sl], m4);
    }
    float mux = m01.x, muy = m01.y, bxx = m23.x, byy = m23.y, bxy = m4;
    float mux2 = mux * mux, muy2 = muy * muy, muxy = mux * muy;
    float sx = bxx - mux2, sy = byy - muy2, sxy = bxy - muxy;
    float num = fmaf(2.f, muxy, C1f) * fmaf(2.f, sxy, C2f);
    float den = (mux2 + muy2 + C1f) * (sx + sy + C2f);
    fsum += 1.f - num * __builtin_amdgcn_rcpf(den);
  }
  lsum += (double)fsum;
}

// ---- Kernel B: D-blur + SSIM + mean-reduce ----
// grid = (h=S, n, dchunk=4); block = 192 (w). Register ring of 11 planes,
// ping-pong register staging one 11-batch ahead; fully unrolled (48 steps).
__global__ __launch_bounds__(192) void k_blurD_ssim(
    const __half2* __restrict__ p01, const __half2* __restrict__ p23,
    const __half* __restrict__ p4, double* __restrict__ acc, GaussW Wt) {
  const int w = threadIdx.x;
  const int h = blockIdx.x;
  const long long n = blockIdx.y;
  const int d0 = (int)blockIdx.z * DCH;
  const long long base = n * S3 + (long long)h * S + w;
  const __half2* q01 = p01 + base;
  const __half2* q23 = p23 + base;
  const __half* q4 = p4 + base;

  float2 r01[K], r23[K];
  float r4[K];
  // preload counters 0..9 -> slots 0..9 (planes d0-5..d0+4, guard low)
#pragma unroll
  for (int c = 0; c < K - 1; ++c) {
    int d = d0 - R + c;
    if ((unsigned)d < (unsigned)S) {
      long long o = (long long)d * S2;
      r01[c] = __half22float2(q01[o]);
      r23[c] = __half22float2(q23[o]);
      r4[c] = __half2float(q4[o]);
    } else {
      r01[c] = make_float2(0.f, 0.f);
      r23[c] = make_float2(0.f, 0.f);
      r4[c] = 0.f;
    }
  }
  r01[K - 1] = make_float2(0.f, 0.f);
  r23[K - 1] = make_float2(0.f, 0.f);
  r4[K - 1] = 0.f;

  __half2 sa0[K], sb0[K], sa1[K], sb1[K];
  __half se0[K], se1[K];
  double lsum = 0.0;

  // plane ranges: d0+5..d0+15, d0+16..d0+26, d0+27..d0+37 (max 181: safe),
  // d0+38..d0+48 and d0+49..d0+52 guarded (max 196).
  stageB<K, false>(q01, q23, q4, d0 + 5, sa0, sb0, se0);   // counters 10..20
  stageB<K, false>(q01, q23, q4, d0 + 16, sa1, sb1, se1);  // counters 21..31
  consumeB<K>(sa0, sb0, se0, Wt, r01, r23, r4, lsum);      // t = 0..10
  stageB<K, false>(q01, q23, q4, d0 + 27, sa0, sb0, se0);  // counters 32..42
  consumeB<K>(sa1, sb1, se1, Wt, r01, r23, r4, lsum);      // t = 11..21
  stageB<K, true>(q01, q23, q4, d0 + 38, sa1, sb1, se1);   // counters 43..53
  consumeB<K>(sa0, sb0, se0, Wt, r01, r23, r4, lsum);      // t = 22..32
  stageB<4, true>(q01, q23, q4, d0 + 49, sa0, sb0, se0);   // counters 54..57
  consumeB<K>(sa1, sb1, se1, Wt, r01, r23, r4, lsum);      // t = 33..43
  consumeB<4>(sa0, sb0, se0, Wt, r01, r23, r4, lsum);      // t = 44..47

  // block reduction: wave shuffle -> LDS -> one atomic per block
  double v = lsum;
#pragma unroll
  for (int o = 32; o > 0; o >>= 1) v += __shfl_down(v, o, 64);
  __shared__ double wsum[3];
  int lane = threadIdx.x & 63, wv = threadIdx.x >> 6;
  if (lane == 0) wsum[wv] = v;
  __syncthreads();
  if (threadIdx.x == 0) atomicAdd(acc, wsum[0] + wsum[1] + wsum[2]);
}

}  // namespace

extern "C" void kernel_launch(void* const* d_in, const int* in_sizes, int n_in,
                              void* d_out, int out_size, void* d_ws, size_t ws_size,
                              hipStream_t stream) {
  (void)in_sizes; (void)n_in; (void)out_size;
  const float* gt = (const float*)d_in[0];
  const float* pr = (const float*)d_in[1];
  float* out = (float*)d_out;
  double* acc = (double*)d_ws;

  GaussW W;
  {
    double gg[K], sum = 0.0;
    for (int i = 0; i < K; ++i) {
      double x = (double)(i - K / 2);
      gg[i] = exp(-(x * x) / (2.0 * 1.5 * 1.5)) / (sqrt(2.0 * M_PI) * 1.5);
      sum += gg[i];
    }
    for (int i = 0; i < K; ++i) W.g[i] = (float)(gg[i] / sum);
  }

  auto run = [&](long long base_n, int nb) {
    size_t vox = (size_t)nb * S3;
    __half2* p01 = (__half2*)((char*)d_ws + 256);
    __half2* p23 = p01 + vox;
    __half* p4 = (__half*)(p23 + vox);
    k_blurWH<<<dim3(S, S / HCH, nb), dim3(192), 0, stream>>>(
        gt, pr, p01, p23, p4, base_n * S3, W);
    k_blurD_ssim<<<dim3(S, nb, S / DCH), dim3(192), 0, stream>>>(
        p01, p23, p4, acc, W);
  };
  auto need = [](int nb) { return (size_t)256 + (size_t)nb * S3 * 10; };

  k_init<<<dim3(1), dim3(1), 0, stream>>>(acc);
  if (ws_size >= need(4)) {
    run(0, 4);
  } else if (ws_size >= need(2)) {
    run(0, 2);
    run(2, 2);
  } else {
    for (int g = 0; g < NB; ++g) run(g, 1);
  }
  k_final<<<dim3(1), dim3(1), 0, stream>>>(acc, out);
}

// Round 6
// 429.208 us; speedup vs baseline: 2.3537x; 1.0603x over previous
//
#include <hip/hip_runtime.h>
#include <hip/hip_fp16.h>
#include <math.h>

namespace {
constexpr int S = 192;
constexpr long long S2 = (long long)S * S;
constexpr long long S3 = (long long)S * S2;
constexpr int NB = 4;
constexpr int K = 11;
constexpr int R = 5;
constexpr int HCH = 32;   // A: h-outputs per block (6 chunks)
constexpr int DCH = 48;   // B: d-outputs per block (4 chunks)
constexpr float C1f = 1e-4f;
constexpr float C2f = 9e-4f;

struct GaussW { float g[K]; };

__global__ void k_init(double* acc) { *acc = 0.0; }

__global__ void k_final(const double* __restrict__ acc, float* __restrict__ out) {
  out[0] = (float)(acc[0] / (double)(NB * S3));
}

// ======================= Kernel A =======================
// Fused W+H blur. Fields 0..3 (mux,muy,bxx,byy) packed as 4xfp16 in uint2;
// field 4 (bxy) separate fp16. NO long-lived register staging arrays
// (R5's la/lb spilled to scratch -> 2x write amplification): loads go
// straight to LDS within stageA; TLP hides the latency.

template <int NROWS, bool GUARD>
__device__ __forceinline__ void stageA(const float* pg, const float* pp, int r0,
                                       int w, float2 (*rb)[208]) {
  float la[NROWS], lb[NROWS];  // transient: dead before consume
#pragma unroll
  for (int j = 0; j < NROWS; ++j) {
    int r = r0 + j;
    bool ok = !GUARD || ((unsigned)r < (unsigned)S);
    la[j] = ok ? pg[(long long)r * S + w] : 0.f;
    lb[j] = ok ? pp[(long long)r * S + w] : 0.f;
  }
#pragma unroll
  for (int j = 0; j < NROWS; ++j) rb[j][8 + w] = make_float2(la[j], lb[j]);
}

template <int NROWS, bool EMITALL>
__device__ __forceinline__ void consumeA(
    const float2 (*rb)[208], int w, const GaussW& Wt,
    float2 (&w01)[K], float2 (&w23)[K], float (&w4v)[K],
    uint2* p0123, __half* p4, long long obase, int hbase) {
#pragma unroll
  for (int j = 0; j < NROWS; ++j) {
    // W-blur the 5 products for staged row j
    float2 s01 = make_float2(0.f, 0.f), s23 = make_float2(0.f, 0.f);
    float s4 = 0.f;
#pragma unroll
    for (int i = 0; i < K; ++i) {
      float2 ab = rb[j][w + 3 + i];
      float g = Wt.g[i];
      s01.x = fmaf(g, ab.x, s01.x);
      s01.y = fmaf(g, ab.y, s01.y);
      float ta = g * ab.x, tb = g * ab.y;
      s23.x = fmaf(ta, ab.x, s23.x);
      s23.y = fmaf(tb, ab.y, s23.y);
      s4 = fmaf(ta, ab.y, s4);
    }
    w01[j] = s01; w23[j] = s23; w4v[j] = s4;  // ring slot = counter % 11 = j
    if (EMITALL || j == K - 1) {              // compile-time
      float2 m01 = make_float2(0.f, 0.f), m23 = make_float2(0.f, 0.f);
      float m4 = 0.f;
#pragma unroll
      for (int i = 0; i < K; ++i) {
        const int sl = (j + 1 + i) % K;       // compile-time
        float g = Wt.g[i];
        m01.x = fmaf(g, w01[sl].x, m01.x);
        m01.y = fmaf(g, w01[sl].y, m01.y);
        m23.x = fmaf(g, w23[sl].x, m23.x);
        m23.y = fmaf(g, w23[sl].y, m23.y);
        m4 = fmaf(g, w4v[sl], m4);
      }
      long long o = obase + (long long)(hbase + j) * S;
      __half2 h01 = __floats2half2_rn(m01.x, m01.y);
      __half2 h23 = __floats2half2_rn(m23.x, m23.y);
      uint2 v;
      v.x = __builtin_bit_cast(unsigned, h01);
      v.y = __builtin_bit_cast(unsigned, h23);
      p0123[o] = v;
      p4[o] = __float2half(m4);
    }
  }
}

// grid = (dz=S, hchunk=6, n); block = 192 (w). Batches of 11,11,11,9 rows;
// single 18.4 KB LDS buffer (8 blocks/CU cap), 2 barriers per batch.
// Row ranges: b0 = h0-5..h0+5 (GUARD: neg), b1 <= 176, b2 <= 187 (safe),
// b3 = h0+28..h0+36 <= 196 (GUARD).
__global__ __launch_bounds__(192) void k_blurWH(
    const float* __restrict__ gt, const float* __restrict__ pr,
    uint2* __restrict__ p0123, __half* __restrict__ p4,
    long long in_base, GaussW Wt) {
  __shared__ float2 rowbuf[K][208];  // [8..199] data, [0..7]/[200..207] pads
  const int w = threadIdx.x;
  const int dz = blockIdx.x;
  const int h0 = (int)blockIdx.y * HCH;
  const long long n = blockIdx.z;
  const float* pg = gt + in_base + (n * S + dz) * S2;
  const float* pp = pr + in_base + (n * S + dz) * S2;
  const long long obase = (n * S + dz) * S2 + w;

  if (w < 176) {  // zero halo pads once (before first barrier)
    int j = w >> 4, q = w & 15;
    rowbuf[j][(q < 8) ? q : (192 + q)] = make_float2(0.f, 0.f);
  }

  float2 w01[K], w23[K];
  float w4v[K];  // no init needed: batch0 writes all 11 slots before 1st emit

  stageA<K, true>(pg, pp, h0 - R, w, rowbuf);
  __syncthreads();
  consumeA<K, false>(rowbuf, w, Wt, w01, w23, w4v, p0123, p4, obase, h0 - 10);
  __syncthreads();
  stageA<K, false>(pg, pp, h0 + 6, w, rowbuf);
  __syncthreads();
  consumeA<K, true>(rowbuf, w, Wt, w01, w23, w4v, p0123, p4, obase, h0 + 1);
  __syncthreads();
  stageA<K, false>(pg, pp, h0 + 17, w, rowbuf);
  __syncthreads();
  consumeA<K, true>(rowbuf, w, Wt, w01, w23, w4v, p0123, p4, obase, h0 + 12);
  __syncthreads();
  stageA<9, true>(pg, pp, h0 + 28, w, rowbuf);
  __syncthreads();
  consumeA<9, true>(rowbuf, w, Wt, w01, w23, w4v, p0123, p4, obase, h0 + 23);
}

// ======================= Kernel B =======================

template <int N, bool GUARD>
__device__ __forceinline__ void stageB(const uint2* q0123, const __half* q4,
                                       int plane0, uint2 (&sab)[K], __half (&se)[K]) {
#pragma unroll
  for (int j = 0; j < N; ++j) {
    int d = plane0 + j;
    bool ok = !GUARD || ((unsigned)d < (unsigned)S);
    long long o = (long long)d * S2;
    sab[j] = ok ? q0123[o] : make_uint2(0u, 0u);  // fp16 bits 0 == 0.0
    se[j] = ok ? q4[o] : __float2half(0.f);
  }
}

template <int NOUT>
__device__ __forceinline__ void consumeB(
    const uint2 (&sab)[K], const __half (&se)[K],
    const GaussW& Wt, float2 (&r01)[K], float2 (&r23)[K], float (&r4)[K],
    double& lsum) {
  float fsum = 0.f;
#pragma unroll
  for (int j = 0; j < NOUT; ++j) {
    const int sw = (10 + j) % K;              // compile-time commit slot
    r01[sw] = __half22float2(__builtin_bit_cast(__half2, sab[j].x));
    r23[sw] = __half22float2(__builtin_bit_cast(__half2, sab[j].y));
    r4[sw] = __half2float(se[j]);
    float2 m01 = make_float2(0.f, 0.f), m23 = make_float2(0.f, 0.f);
    float m4 = 0.f;
#pragma unroll
    for (int i = 0; i < K; ++i) {
      const int sl = (j + i) % K;             // compile-time
      float g = Wt.g[i];
      m01.x = fmaf(g, r01[sl].x, m01.x);
      m01.y = fmaf(g, r01[sl].y, m01.y);
      m23.x = fmaf(g, r23[sl].x, m23.x);
      m23.y = fmaf(g, r23[sl].y, m23.y);
      m4 = fmaf(g, r4[sl], m4);
    }
    float mux = m01.x, muy = m01.y, bxx = m23.x, byy = m23.y, bxy = m4;
    float mux2 = mux * mux, muy2 = muy * muy, muxy = mux * muy;
    float sx = bxx - mux2, sy = byy - muy2, sxy = bxy - muxy;
    float num = fmaf(2.f, muxy, C1f) * fmaf(2.f, sxy, C2f);
    float den = (mux2 + muy2 + C1f) * (sx + sy + C2f);
    fsum += 1.f - num * __builtin_amdgcn_rcpf(den);
  }
  lsum += (double)fsum;
}

// D-blur + SSIM + mean-reduce. grid = (h=S, n, dchunk=4); block = 192 (w).
// Register ring of 11 planes, ping-pong staging one 11-batch ahead.
__global__ __launch_bounds__(192) void k_blurD_ssim(
    const uint2* __restrict__ p0123, const __half* __restrict__ p4,
    double* __restrict__ acc, GaussW Wt) {
  const int w = threadIdx.x;
  const int h = blockIdx.x;
  const long long n = blockIdx.y;
  const int d0 = (int)blockIdx.z * DCH;
  const long long base = n * S3 + (long long)h * S + w;
  const uint2* q0123 = p0123 + base;
  const __half* q4 = p4 + base;

  float2 r01[K], r23[K];
  float r4[K];
  // preload counters 0..9 -> slots 0..9 (planes d0-5..d0+4, guard low)
#pragma unroll
  for (int c = 0; c < K - 1; ++c) {
    int d = d0 - R + c;
    if ((unsigned)d < (unsigned)S) {
      long long o = (long long)d * S2;
      uint2 v = q0123[o];
      r01[c] = __half22float2(__builtin_bit_cast(__half2, v.x));
      r23[c] = __half22float2(__builtin_bit_cast(__half2, v.y));
      r4[c] = __half2float(q4[o]);
    } else {
      r01[c] = make_float2(0.f, 0.f);
      r23[c] = make_float2(0.f, 0.f);
      r4[c] = 0.f;
    }
  }
  r01[K - 1] = make_float2(0.f, 0.f);
  r23[K - 1] = make_float2(0.f, 0.f);
  r4[K - 1] = 0.f;

  uint2 sab0[K], sab1[K];
  __half se0[K], se1[K];
  double lsum = 0.0;

  // plane ranges: d0+5..15, d0+16..26, d0+27..37 (max 181: safe);
  // d0+38..48 and d0+49..52 guarded (max 196).
  stageB<K, false>(q0123, q4, d0 + 5, sab0, se0);   // counters 10..20
  stageB<K, false>(q0123, q4, d0 + 16, sab1, se1);  // counters 21..31
  consumeB<K>(sab0, se0, Wt, r01, r23, r4, lsum);   // t = 0..10
  stageB<K, false>(q0123, q4, d0 + 27, sab0, se0);  // counters 32..42
  consumeB<K>(sab1, se1, Wt, r01, r23, r4, lsum);   // t = 11..21
  stageB<K, true>(q0123, q4, d0 + 38, sab1, se1);   // counters 43..53
  consumeB<K>(sab0, se0, Wt, r01, r23, r4, lsum);   // t = 22..32
  stageB<4, true>(q0123, q4, d0 + 49, sab0, se0);   // counters 54..57
  consumeB<K>(sab1, se1, Wt, r01, r23, r4, lsum);   // t = 33..43
  consumeB<4>(sab0, se0, Wt, r01, r23, r4, lsum);   // t = 44..47

  // block reduction: wave shuffle -> LDS -> one atomic per block
  double v = lsum;
#pragma unroll
  for (int o = 32; o > 0; o >>= 1) v += __shfl_down(v, o, 64);
  __shared__ double wsum[3];
  int lane = threadIdx.x & 63, wv = threadIdx.x >> 6;
  if (lane == 0) wsum[wv] = v;
  __syncthreads();
  if (threadIdx.x == 0) atomicAdd(acc, wsum[0] + wsum[1] + wsum[2]);
}

}  // namespace

extern "C" void kernel_launch(void* const* d_in, const int* in_sizes, int n_in,
                              void* d_out, int out_size, void* d_ws, size_t ws_size,
                              hipStream_t stream) {
  (void)in_sizes; (void)n_in; (void)out_size;
  const float* gt = (const float*)d_in[0];
  const float* pr = (const float*)d_in[1];
  float* out = (float*)d_out;
  double* acc = (double*)d_ws;

  GaussW W;
  {
    double gg[K], sum = 0.0;
    for (int i = 0; i < K; ++i) {
      double x = (double)(i - K / 2);
      gg[i] = exp(-(x * x) / (2.0 * 1.5 * 1.5)) / (sqrt(2.0 * M_PI) * 1.5);
      sum += gg[i];
    }
    for (int i = 0; i < K; ++i) W.g[i] = (float)(gg[i] / sum);
  }

  auto run = [&](long long base_n, int nb) {
    size_t vox = (size_t)nb * S3;
    uint2* p0123 = (uint2*)((char*)d_ws + 256);
    __half* p4 = (__half*)(p0123 + vox);
    k_blurWH<<<dim3(S, S / HCH, nb), dim3(192), 0, stream>>>(
        gt, pr, p0123, p4, base_n * S3, W);
    k_blurD_ssim<<<dim3(S, nb, S / DCH), dim3(192), 0, stream>>>(
        p0123, p4, acc, W);
  };
  auto need = [](int nb) { return (size_t)256 + (size_t)nb * S3 * 10; };  // 8+2 B/voxel

  k_init<<<dim3(1), dim3(1), 0, stream>>>(acc);
  if (ws_size >= need(4)) {
    run(0, 4);
  } else if (ws_size >= need(2)) {
    run(0, 2);
    run(2, 2);
  } else {
    for (int g = 0; g < NB; ++g) run(g, 1);
  }
  k_final<<<dim3(1), dim3(1), 0, stream>>>(acc, out);
}